// Round 1
// baseline (4342.988 us; speedup 1.0000x reference)
//
#include <hip/hip_runtime.h>

// ---------------- degree / norm ----------------
__global__ void deg_kernel(const int* __restrict__ dst, int* __restrict__ deg, int E) {
    int e = blockIdx.x * blockDim.x + threadIdx.x;
    if (e < E) atomicAdd(&deg[dst[e]], 1);
}

__global__ void dinv_kernel(const int* __restrict__ deg, float* __restrict__ dinv, int n) {
    int v = blockIdx.x * blockDim.x + threadIdx.x;
    if (v < n) dinv[v] = rsqrtf((float)(deg[v] + 1));  // +1 = self loop; always > 0
}

// ---------------- GEMM1: h[N,128] = x[N,128] @ W[128,128] ----------------
// block = 256 threads computes 32 nodes x 128 cols. Register tile 4 nodes x 4 cols.
__global__ __launch_bounds__(256) void gemm_nk128(const float* __restrict__ x,
                                                  const float* __restrict__ W,
                                                  float* __restrict__ h) {
    __shared__ float xs[32][128];
    int t = threadIdx.x;
    long node0 = (long)blockIdx.x * 32;
    // stage 32 x-rows (16 KB) into LDS, coalesced float4
    const float4* xv = (const float4*)(x + node0 * 128);
    float4* xsv = (float4*)(&xs[0][0]);
#pragma unroll
    for (int i = 0; i < 4; i++) xsv[t + 256 * i] = xv[t + 256 * i];
    __syncthreads();

    int tx = t & 31, ty = t >> 5;   // tx: col group, ty: node group (0..7)
    int c0 = tx * 4;
    float acc[4][4];
#pragma unroll
    for (int i = 0; i < 4; i++)
#pragma unroll
        for (int j = 0; j < 4; j++) acc[i][j] = 0.f;

    for (int k = 0; k < 128; k++) {
        float4 w = *(const float4*)(W + k * 128 + c0);
#pragma unroll
        for (int i = 0; i < 4; i++) {
            float xval = xs[ty + 8 * i][k];   // broadcast within wave (2-way max: free)
            acc[i][0] += xval * w.x;
            acc[i][1] += xval * w.y;
            acc[i][2] += xval * w.z;
            acc[i][3] += xval * w.w;
        }
    }
#pragma unroll
    for (int i = 0; i < 4; i++) {
        long node = node0 + ty + 8 * i;
        *(float4*)(h + node * 128 + c0) = make_float4(acc[i][0], acc[i][1], acc[i][2], acc[i][3]);
    }
}

// ---------------- GEMM2: h3[N,64] = h2[N,128] @ W[128,64] ----------------
// block = 256 computes 32 nodes x 64 cols. Register tile 2 nodes x 4 cols.
__global__ __launch_bounds__(256) void gemm_nk64(const float* __restrict__ x,
                                                 const float* __restrict__ W,
                                                 float* __restrict__ h) {
    __shared__ float xs[32][128];
    int t = threadIdx.x;
    long node0 = (long)blockIdx.x * 32;
    const float4* xv = (const float4*)(x + node0 * 128);
    float4* xsv = (float4*)(&xs[0][0]);
#pragma unroll
    for (int i = 0; i < 4; i++) xsv[t + 256 * i] = xv[t + 256 * i];
    __syncthreads();

    int tx = t & 15, ty = t >> 4;   // tx: col group (0..15), ty: node group (0..15)
    int c0 = tx * 4;
    float acc[2][4];
#pragma unroll
    for (int i = 0; i < 2; i++)
#pragma unroll
        for (int j = 0; j < 4; j++) acc[i][j] = 0.f;

    for (int k = 0; k < 128; k++) {
        float4 w = *(const float4*)(W + k * 64 + c0);
#pragma unroll
        for (int i = 0; i < 2; i++) {
            float xval = xs[ty + 16 * i][k];
            acc[i][0] += xval * w.x;
            acc[i][1] += xval * w.y;
            acc[i][2] += xval * w.z;
            acc[i][3] += xval * w.w;
        }
    }
#pragma unroll
    for (int i = 0; i < 2; i++) {
        long node = node0 + ty + 16 * i;
        *(float4*)(h + node * 64 + c0) = make_float4(acc[i][0], acc[i][1], acc[i][2], acc[i][3]);
    }
}

// ---------------- aggregation layer 1 (128 cols) ----------------
// init: out1 = dinv^2 * h1  (self-loop term)
__global__ void init1_kernel(const float* __restrict__ h1, const float* __restrict__ dinv,
                             float* __restrict__ out1, int n) {
    int i = blockIdx.x * blockDim.x + threadIdx.x;  // float4 index
    if (i < n * 32) {
        int node = i >> 5;
        float di = dinv[node];
        float w = di * di;
        float4 v = ((const float4*)h1)[i];
        ((float4*)out1)[i] = make_float4(w * v.x, w * v.y, w * v.z, w * v.w);
    }
}

// per-edge scatter-add, 32 threads/edge x float4
__global__ void edge1_kernel(const int* __restrict__ src, const int* __restrict__ dst,
                             const float* __restrict__ dinv, const float* __restrict__ h1,
                             float* __restrict__ out1, int E) {
    long idx = (long)blockIdx.x * blockDim.x + threadIdx.x;
    long e = idx >> 5;
    int lane = (int)(idx & 31);
    if (e < E) {
        int s = src[e], d = dst[e];
        float w = dinv[s] * dinv[d];
        float4 v = ((const float4*)(h1 + (long)s * 128))[lane];
        float* o = out1 + (long)d * 128 + lane * 4;
        atomicAdd(o + 0, w * v.x);
        atomicAdd(o + 1, w * v.y);
        atomicAdd(o + 2, w * v.z);
        atomicAdd(o + 3, w * v.w);
    }
}

// h2 = relu(out1 + b1)
__global__ void relubias_kernel(const float* __restrict__ out1, const float* __restrict__ b1,
                                float* __restrict__ h2, int n) {
    int i = blockIdx.x * blockDim.x + threadIdx.x;  // float4 index
    if (i < n * 32) {
        float4 v = ((const float4*)out1)[i];
        float4 b = ((const float4*)b1)[i & 31];
        v.x = fmaxf(v.x + b.x, 0.f);
        v.y = fmaxf(v.y + b.y, 0.f);
        v.z = fmaxf(v.z + b.z, 0.f);
        v.w = fmaxf(v.w + b.w, 0.f);
        ((float4*)h2)[i] = v;
    }
}

// ---------------- aggregation layer 2 (64 cols) ----------------
// init: out = dinv^2 * h3 + b2
__global__ void init2_kernel(const float* __restrict__ h3, const float* __restrict__ dinv,
                             const float* __restrict__ b2, float* __restrict__ out, int n) {
    int i = blockIdx.x * blockDim.x + threadIdx.x;  // float4 index
    if (i < n * 16) {
        int node = i >> 4;
        float di = dinv[node];
        float w = di * di;
        float4 v = ((const float4*)h3)[i];
        float4 b = ((const float4*)b2)[i & 15];
        ((float4*)out)[i] = make_float4(w * v.x + b.x, w * v.y + b.y, w * v.z + b.z, w * v.w + b.w);
    }
}

// per-edge scatter-add, 16 threads/edge x float4
__global__ void edge2_kernel(const int* __restrict__ src, const int* __restrict__ dst,
                             const float* __restrict__ dinv, const float* __restrict__ h3,
                             float* __restrict__ out, int E) {
    long idx = (long)blockIdx.x * blockDim.x + threadIdx.x;
    long e = idx >> 4;
    int lane = (int)(idx & 15);
    if (e < E) {
        int s = src[e], d = dst[e];
        float w = dinv[s] * dinv[d];
        float4 v = ((const float4*)(h3 + (long)s * 64))[lane];
        float* o = out + (long)d * 64 + lane * 4;
        atomicAdd(o + 0, w * v.x);
        atomicAdd(o + 1, w * v.y);
        atomicAdd(o + 2, w * v.z);
        atomicAdd(o + 3, w * v.w);
    }
}

extern "C" void kernel_launch(void* const* d_in, const int* in_sizes, int n_in,
                              void* d_out, int out_size, void* d_ws, size_t ws_size,
                              hipStream_t stream) {
    const float* x  = (const float*)d_in[0];
    const int*   ei = (const int*)d_in[1];
    const float* W1 = (const float*)d_in[2];
    const float* b1 = (const float*)d_in[3];
    const float* W2 = (const float*)d_in[4];
    const float* b2 = (const float*)d_in[5];
    float* out = (float*)d_out;

    const int n = in_sizes[0] / 128;   // 100000
    const int E = in_sizes[1] / 2;     // 1600000
    const int* src = ei;
    const int* dst = ei + E;

    // workspace carve-up (256B aligned)
    char* ws = (char*)d_ws;
    size_t off = 0;
    auto carve = [&](size_t bytes) -> char* {
        char* p = ws + off;
        off += (bytes + 255) & ~(size_t)255;
        return p;
    };
    int*   deg  = (int*)carve((size_t)n * 4);
    float* dinv = (float*)carve((size_t)n * 4);
    float* bufA = (float*)carve((size_t)n * 128 * 4);  // h1, then h2
    float* bufB = (float*)carve((size_t)n * 128 * 4);  // out1, then h3

    hipMemsetAsync(deg, 0, (size_t)n * 4, stream);

    deg_kernel<<<(E + 255) / 256, 256, 0, stream>>>(dst, deg, E);
    dinv_kernel<<<(n + 255) / 256, 256, 0, stream>>>(deg, dinv, n);

    // layer 1
    gemm_nk128<<<n / 32, 256, 0, stream>>>(x, W1, bufA);                       // h1 = x @ W1
    init1_kernel<<<(n * 32 + 255) / 256, 256, 0, stream>>>(bufA, dinv, bufB, n);
    edge1_kernel<<<(int)(((long)E * 32 + 255) / 256), 256, 0, stream>>>(src, dst, dinv, bufA, bufB, E);
    relubias_kernel<<<(n * 32 + 255) / 256, 256, 0, stream>>>(bufB, b1, bufA, n); // h2

    // layer 2
    gemm_nk64<<<n / 32, 256, 0, stream>>>(bufA, W2, bufB);                     // h3 = h2 @ W2
    init2_kernel<<<(n * 16 + 255) / 256, 256, 0, stream>>>(bufB, dinv, b2, out, n);
    edge2_kernel<<<(int)(((long)E * 16 + 255) / 256), 256, 0, stream>>>(src, dst, dinv, bufB, out, E);
}

// Round 2
// 583.233 us; speedup vs baseline: 7.4464x; 7.4464x over previous
//
#include <hip/hip_runtime.h>

// ---------------- degree / norm ----------------
__global__ void deg_kernel(const int* __restrict__ dst, int* __restrict__ deg, int E) {
    int e = blockIdx.x * blockDim.x + threadIdx.x;
    if (e < E) atomicAdd(&deg[dst[e]], 1);
}

__global__ void dinv_kernel(const int* __restrict__ deg, float* __restrict__ dinv, int n) {
    int v = blockIdx.x * blockDim.x + threadIdx.x;
    if (v < n) dinv[v] = rsqrtf((float)(deg[v] + 1));  // +1 = self loop; always > 0
}

// ---------------- exclusive scan of deg -> rowstart (3 kernels) ----------------
__global__ void scan1_kernel(const int* __restrict__ deg, int* __restrict__ rowstart,
                             int* __restrict__ blockSums, int n) {
    __shared__ int tmp[256];
    int t = threadIdx.x;
    int i = blockIdx.x * 256 + t;
    int v = (i < n) ? deg[i] : 0;
    tmp[t] = v;
    __syncthreads();
#pragma unroll
    for (int off = 1; off < 256; off <<= 1) {
        int add = (t >= off) ? tmp[t - off] : 0;
        __syncthreads();
        tmp[t] += add;
        __syncthreads();
    }
    if (i < n) rowstart[i] = tmp[t] - v;   // exclusive within block
    if (t == 255) blockSums[blockIdx.x] = tmp[255];
}

__global__ void scan2_kernel(int* __restrict__ blockSums, int nb) {
    __shared__ int tmp[512];
    int t = threadIdx.x;
    int v = (t < nb) ? blockSums[t] : 0;
    tmp[t] = v;
    __syncthreads();
#pragma unroll
    for (int off = 1; off < 512; off <<= 1) {
        int add = (t >= off) ? tmp[t - off] : 0;
        __syncthreads();
        tmp[t] += add;
        __syncthreads();
    }
    if (t < nb) blockSums[t] = tmp[t] - v;  // exclusive block offsets
}

__global__ void scan3_kernel(int* __restrict__ rowstart, const int* __restrict__ blockSums,
                             int* __restrict__ cursor, int n) {
    int i = blockIdx.x * blockDim.x + threadIdx.x;
    if (i < n) {
        int r = rowstart[i] + blockSums[i >> 8];
        rowstart[i] = r;
        cursor[i] = r;
    }
}

// ---------------- counting-sort edges by dst; precompute weights ----------------
__global__ void sort_kernel(const int* __restrict__ src, const int* __restrict__ dst,
                            const float* __restrict__ dinv, int* __restrict__ cursor,
                            int* __restrict__ srcSorted, float* __restrict__ wSorted, int E) {
    int e = blockIdx.x * blockDim.x + threadIdx.x;
    if (e < E) {
        int s = src[e], d = dst[e];
        int pos = atomicAdd(&cursor[d], 1);
        srcSorted[pos] = s;
        wSorted[pos] = dinv[s] * dinv[d];
    }
}

// ---------------- GEMM1: h[N,128] = x[N,128] @ W[128,128] ----------------
__global__ __launch_bounds__(256) void gemm_nk128(const float* __restrict__ x,
                                                  const float* __restrict__ W,
                                                  float* __restrict__ h) {
    __shared__ float xs[32][128];
    int t = threadIdx.x;
    long node0 = (long)blockIdx.x * 32;
    const float4* xv = (const float4*)(x + node0 * 128);
    float4* xsv = (float4*)(&xs[0][0]);
#pragma unroll
    for (int i = 0; i < 4; i++) xsv[t + 256 * i] = xv[t + 256 * i];
    __syncthreads();

    int tx = t & 31, ty = t >> 5;
    int c0 = tx * 4;
    float acc[4][4];
#pragma unroll
    for (int i = 0; i < 4; i++)
#pragma unroll
        for (int j = 0; j < 4; j++) acc[i][j] = 0.f;

    for (int k = 0; k < 128; k++) {
        float4 w = *(const float4*)(W + k * 128 + c0);
#pragma unroll
        for (int i = 0; i < 4; i++) {
            float xval = xs[ty + 8 * i][k];
            acc[i][0] += xval * w.x;
            acc[i][1] += xval * w.y;
            acc[i][2] += xval * w.z;
            acc[i][3] += xval * w.w;
        }
    }
#pragma unroll
    for (int i = 0; i < 4; i++) {
        long node = node0 + ty + 8 * i;
        *(float4*)(h + node * 128 + c0) = make_float4(acc[i][0], acc[i][1], acc[i][2], acc[i][3]);
    }
}

// ---------------- GEMM2: h3[N,64] = h2[N,128] @ W[128,64] ----------------
__global__ __launch_bounds__(256) void gemm_nk64(const float* __restrict__ x,
                                                 const float* __restrict__ W,
                                                 float* __restrict__ h) {
    __shared__ float xs[32][128];
    int t = threadIdx.x;
    long node0 = (long)blockIdx.x * 32;
    const float4* xv = (const float4*)(x + node0 * 128);
    float4* xsv = (float4*)(&xs[0][0]);
#pragma unroll
    for (int i = 0; i < 4; i++) xsv[t + 256 * i] = xv[t + 256 * i];
    __syncthreads();

    int tx = t & 15, ty = t >> 4;
    int c0 = tx * 4;
    float acc[2][4];
#pragma unroll
    for (int i = 0; i < 2; i++)
#pragma unroll
        for (int j = 0; j < 4; j++) acc[i][j] = 0.f;

    for (int k = 0; k < 128; k++) {
        float4 w = *(const float4*)(W + k * 64 + c0);
#pragma unroll
        for (int i = 0; i < 2; i++) {
            float xval = xs[ty + 16 * i][k];
            acc[i][0] += xval * w.x;
            acc[i][1] += xval * w.y;
            acc[i][2] += xval * w.z;
            acc[i][3] += xval * w.w;
        }
    }
#pragma unroll
    for (int i = 0; i < 2; i++) {
        long node = node0 + ty + 16 * i;
        *(float4*)(h + node * 64 + c0) = make_float4(acc[i][0], acc[i][1], acc[i][2], acc[i][3]);
    }
}

// ---------------- gather-aggregate layer 1 (128 cols) + bias + relu ----------------
// 32 threads per node, 8 nodes per 256-block
__global__ __launch_bounds__(256) void gather1_kernel(
        const int* __restrict__ srcSorted, const float* __restrict__ wSorted,
        const int* __restrict__ rowstart, const int* __restrict__ deg,
        const float* __restrict__ dinv, const float* __restrict__ h1,
        const float* __restrict__ b1, float* __restrict__ h2, int n) {
    int g = blockIdx.x * 8 + (threadIdx.x >> 5);
    int lane = threadIdx.x & 31;
    if (g >= n) return;
    float di = dinv[g];
    float w0 = di * di;
    float4 v = ((const float4*)(h1 + (long)g * 128))[lane];
    float4 acc = make_float4(w0 * v.x, w0 * v.y, w0 * v.z, w0 * v.w);
    int beg = rowstart[g], end = beg + deg[g];
    for (int e = beg; e < end; e++) {
        int s = srcSorted[e];          // broadcast within group
        float w = wSorted[e];
        float4 u = ((const float4*)(h1 + (long)s * 128))[lane];
        acc.x += w * u.x;
        acc.y += w * u.y;
        acc.z += w * u.z;
        acc.w += w * u.w;
    }
    float4 b = ((const float4*)b1)[lane];
    acc.x = fmaxf(acc.x + b.x, 0.f);
    acc.y = fmaxf(acc.y + b.y, 0.f);
    acc.z = fmaxf(acc.z + b.z, 0.f);
    acc.w = fmaxf(acc.w + b.w, 0.f);
    ((float4*)(h2 + (long)g * 128))[lane] = acc;
}

// ---------------- gather-aggregate layer 2 (64 cols) + bias ----------------
// 16 threads per node, 16 nodes per 256-block
__global__ __launch_bounds__(256) void gather2_kernel(
        const int* __restrict__ srcSorted, const float* __restrict__ wSorted,
        const int* __restrict__ rowstart, const int* __restrict__ deg,
        const float* __restrict__ dinv, const float* __restrict__ h3,
        const float* __restrict__ b2, float* __restrict__ out, int n) {
    int g = blockIdx.x * 16 + (threadIdx.x >> 4);
    int lane = threadIdx.x & 15;
    if (g >= n) return;
    float di = dinv[g];
    float w0 = di * di;
    float4 v = ((const float4*)(h3 + (long)g * 64))[lane];
    float4 acc = make_float4(w0 * v.x, w0 * v.y, w0 * v.z, w0 * v.w);
    int beg = rowstart[g], end = beg + deg[g];
    for (int e = beg; e < end; e++) {
        int s = srcSorted[e];
        float w = wSorted[e];
        float4 u = ((const float4*)(h3 + (long)s * 64))[lane];
        acc.x += w * u.x;
        acc.y += w * u.y;
        acc.z += w * u.z;
        acc.w += w * u.w;
    }
    float4 b = ((const float4*)b2)[lane];
    acc.x += b.x;
    acc.y += b.y;
    acc.z += b.z;
    acc.w += b.w;
    ((float4*)(out + (long)g * 64))[lane] = acc;
}

extern "C" void kernel_launch(void* const* d_in, const int* in_sizes, int n_in,
                              void* d_out, int out_size, void* d_ws, size_t ws_size,
                              hipStream_t stream) {
    const float* x  = (const float*)d_in[0];
    const int*   ei = (const int*)d_in[1];
    const float* W1 = (const float*)d_in[2];
    const float* b1 = (const float*)d_in[3];
    const float* W2 = (const float*)d_in[4];
    const float* b2 = (const float*)d_in[5];
    float* out = (float*)d_out;

    const int n = in_sizes[0] / 128;   // 100000
    const int E = in_sizes[1] / 2;     // 1600000
    const int* src = ei;
    const int* dst = ei + E;
    const int nb = (n + 255) / 256;    // scan blocks (391)

    // workspace carve-up (256B aligned)
    char* ws = (char*)d_ws;
    size_t off = 0;
    auto carve = [&](size_t bytes) -> char* {
        char* p = ws + off;
        off += (bytes + 255) & ~(size_t)255;
        return p;
    };
    int*   deg       = (int*)carve((size_t)n * 4);
    float* dinv      = (float*)carve((size_t)n * 4);
    int*   rowstart  = (int*)carve((size_t)n * 4);
    int*   cursor    = (int*)carve((size_t)n * 4);
    int*   blockSums = (int*)carve((size_t)nb * 4);
    int*   srcSorted = (int*)carve((size_t)E * 4);
    float* wSorted   = (float*)carve((size_t)E * 4);
    float* bufA      = (float*)carve((size_t)n * 128 * 4);  // h1, then h2
    float* bufB      = (float*)carve((size_t)n * 128 * 4);  // h3

    hipMemsetAsync(deg, 0, (size_t)n * 4, stream);

    // degree, norm, CSR build
    deg_kernel<<<(E + 255) / 256, 256, 0, stream>>>(dst, deg, E);
    dinv_kernel<<<(n + 255) / 256, 256, 0, stream>>>(deg, dinv, n);
    scan1_kernel<<<nb, 256, 0, stream>>>(deg, rowstart, blockSums, n);
    scan2_kernel<<<1, 512, 0, stream>>>(blockSums, nb);
    scan3_kernel<<<(n + 255) / 256, 256, 0, stream>>>(rowstart, blockSums, cursor, n);
    sort_kernel<<<(E + 255) / 256, 256, 0, stream>>>(src, dst, dinv, cursor, srcSorted, wSorted, E);

    // layer 1: h1 = x@W1 ; h2 = relu(agg(h1) + b1)
    gemm_nk128<<<n / 32, 256, 0, stream>>>(x, W1, bufA);
    gather1_kernel<<<(n + 7) / 8, 256, 0, stream>>>(srcSorted, wSorted, rowstart, deg, dinv,
                                                    bufA, b1, bufB, n);

    // layer 2: h3 = h2@W2 ; out = agg(h3) + b2
    gemm_nk64<<<n / 32, 256, 0, stream>>>(bufB, W2, bufA);
    gather2_kernel<<<(n + 15) / 16, 256, 0, stream>>>(srcSorted, wSorted, rowstart, deg, dinv,
                                                      bufA, b2, out, n);
}

// Round 4
// 545.862 us; speedup vs baseline: 7.9562x; 1.0685x over previous
//
#include <hip/hip_runtime.h>

// ---------------- degree / norm ----------------
__global__ void deg_kernel(const int* __restrict__ dst, int* __restrict__ deg, int E) {
    int e = blockIdx.x * blockDim.x + threadIdx.x;
    if (e < E) atomicAdd(&deg[dst[e]], 1);
}

__global__ void dinv_kernel(const int* __restrict__ deg, float* __restrict__ dinv, int n) {
    int v = blockIdx.x * blockDim.x + threadIdx.x;
    if (v < n) dinv[v] = rsqrtf((float)(deg[v] + 1));  // +1 = self loop; always > 0
}

// ---------------- exclusive scan of deg -> rowstart ----------------
__global__ void scan1_kernel(const int* __restrict__ deg, int* __restrict__ rowstart,
                             int* __restrict__ blockSums, int n) {
    __shared__ int tmp[256];
    int t = threadIdx.x;
    int i = blockIdx.x * 256 + t;
    int v = (i < n) ? deg[i] : 0;
    tmp[t] = v;
    __syncthreads();
#pragma unroll
    for (int off = 1; off < 256; off <<= 1) {
        int add = (t >= off) ? tmp[t - off] : 0;
        __syncthreads();
        tmp[t] += add;
        __syncthreads();
    }
    if (i < n) rowstart[i] = tmp[t] - v;
    if (t == 255) blockSums[blockIdx.x] = tmp[255];
}

__global__ void scan2_kernel(int* __restrict__ blockSums, int nb) {
    __shared__ int tmp[512];
    int t = threadIdx.x;
    int v = (t < nb) ? blockSums[t] : 0;
    tmp[t] = v;
    __syncthreads();
#pragma unroll
    for (int off = 1; off < 512; off <<= 1) {
        int add = (t >= off) ? tmp[t - off] : 0;
        __syncthreads();
        tmp[t] += add;
        __syncthreads();
    }
    if (t < nb) blockSums[t] = tmp[t] - v;
}

__global__ void scan3_kernel(int* __restrict__ rowstart, const int* __restrict__ blockSums,
                             int* __restrict__ cursor, int n) {
    int i = blockIdx.x * blockDim.x + threadIdx.x;
    if (i < n) {
        int r = rowstart[i] + blockSums[i >> 8];
        rowstart[i] = r;
        cursor[i] = r;
    }
}

// ---------------- counting-sort edges by dst; pack (src, weight) ----------------
__global__ void sort_kernel(const int* __restrict__ src, const int* __restrict__ dst,
                            const float* __restrict__ dinv, int* __restrict__ cursor,
                            int2* __restrict__ edgeSorted, int E) {
    int e = blockIdx.x * blockDim.x + threadIdx.x;
    if (e < E) {
        int s = src[e], d = dst[e];
        int pos = atomicAdd(&cursor[d], 1);
        int2 p;
        p.x = s;
        p.y = __float_as_int(dinv[s] * dinv[d]);
        edgeSorted[pos] = p;
    }
}

// ---------------- GEMM1: h1[N,128] = x[N,128] @ W1[128,128] (all fp32) ----------------
__global__ __launch_bounds__(256) void gemm_nk128(const float* __restrict__ x,
                                                  const float* __restrict__ W,
                                                  float* __restrict__ h) {
    __shared__ float xs[32][128];
    int t = threadIdx.x;
    size_t node0 = (size_t)blockIdx.x * 32;
    const float4* xv = (const float4*)(x + node0 * 128);
    float4* xsv = (float4*)(&xs[0][0]);
#pragma unroll
    for (int i = 0; i < 4; i++) xsv[t + 256 * i] = xv[t + 256 * i];
    __syncthreads();

    int tx = t & 31, ty = t >> 5;
    int c0 = tx * 4;
    float acc[4][4];
#pragma unroll
    for (int i = 0; i < 4; i++)
#pragma unroll
        for (int j = 0; j < 4; j++) acc[i][j] = 0.f;

    for (int k = 0; k < 128; k++) {
        float4 w = *(const float4*)(W + k * 128 + c0);
#pragma unroll
        for (int i = 0; i < 4; i++) {
            float xval = xs[ty + 8 * i][k];
            acc[i][0] += xval * w.x;
            acc[i][1] += xval * w.y;
            acc[i][2] += xval * w.z;
            acc[i][3] += xval * w.w;
        }
    }
#pragma unroll
    for (int i = 0; i < 4; i++) {
        size_t node = node0 + ty + 8 * i;
        *(float4*)(h + node * 128 + c0) = make_float4(acc[i][0], acc[i][1], acc[i][2], acc[i][3]);
    }
}

// ---------------- GEMM2: h3[N,64] = h2[N,128] @ W2[128,64] (all fp32) ----------------
__global__ __launch_bounds__(256) void gemm_nk64(const float* __restrict__ x,
                                                 const float* __restrict__ W,
                                                 float* __restrict__ h) {
    __shared__ float xs[32][128];
    int t = threadIdx.x;
    size_t node0 = (size_t)blockIdx.x * 32;
    const float4* xv = (const float4*)(x + node0 * 128);
    float4* xsv = (float4*)(&xs[0][0]);
#pragma unroll
    for (int i = 0; i < 4; i++) xsv[t + 256 * i] = xv[t + 256 * i];
    __syncthreads();

    int tx = t & 15, ty = t >> 4;
    int c0 = tx * 4;
    float acc[2][4];
#pragma unroll
    for (int i = 0; i < 2; i++)
#pragma unroll
        for (int j = 0; j < 4; j++) acc[i][j] = 0.f;

    for (int k = 0; k < 128; k++) {
        float4 w = *(const float4*)(W + k * 64 + c0);
#pragma unroll
        for (int i = 0; i < 2; i++) {
            float xval = xs[ty + 16 * i][k];
            acc[i][0] += xval * w.x;
            acc[i][1] += xval * w.y;
            acc[i][2] += xval * w.z;
            acc[i][3] += xval * w.w;
        }
    }
#pragma unroll
    for (int i = 0; i < 2; i++) {
        size_t node = node0 + ty + 16 * i;
        *(float4*)(h + node * 64 + c0) = make_float4(acc[i][0], acc[i][1], acc[i][2], acc[i][3]);
    }
}

// ---------------- gather layer 1 (128 f32 cols) + bias + relu ----------------
// 32 lanes per node, 8 nodes per 256-block; 4x unrolled edge loop
__global__ __launch_bounds__(256) void gather1_kernel(
        const int2* __restrict__ eS, const int* __restrict__ rowstart,
        const int* __restrict__ deg, const float* __restrict__ dinv,
        const float* __restrict__ h1, const float* __restrict__ b1,
        float* __restrict__ h2, int n) {
    int g = blockIdx.x * 8 + (threadIdx.x >> 5);
    int lane = threadIdx.x & 31;
    if (g >= n) return;
    float di = dinv[g];
    float w0 = di * di;
    float4 v = ((const float4*)(h1 + (size_t)g * 128))[lane];
    float4 acc = make_float4(w0 * v.x, w0 * v.y, w0 * v.z, w0 * v.w);
    int beg = rowstart[g], end = beg + deg[g];
    int e = beg;
    for (; e + 4 <= end; e += 4) {
        int2 p0 = eS[e], p1 = eS[e + 1], p2 = eS[e + 2], p3 = eS[e + 3];
        float4 u0 = ((const float4*)(h1 + (size_t)p0.x * 128))[lane];
        float4 u1 = ((const float4*)(h1 + (size_t)p1.x * 128))[lane];
        float4 u2 = ((const float4*)(h1 + (size_t)p2.x * 128))[lane];
        float4 u3 = ((const float4*)(h1 + (size_t)p3.x * 128))[lane];
        float w0f = __int_as_float(p0.y), w1f = __int_as_float(p1.y);
        float w2f = __int_as_float(p2.y), w3f = __int_as_float(p3.y);
        acc.x += w0f * u0.x; acc.y += w0f * u0.y; acc.z += w0f * u0.z; acc.w += w0f * u0.w;
        acc.x += w1f * u1.x; acc.y += w1f * u1.y; acc.z += w1f * u1.z; acc.w += w1f * u1.w;
        acc.x += w2f * u2.x; acc.y += w2f * u2.y; acc.z += w2f * u2.z; acc.w += w2f * u2.w;
        acc.x += w3f * u3.x; acc.y += w3f * u3.y; acc.z += w3f * u3.z; acc.w += w3f * u3.w;
    }
    for (; e < end; e++) {
        int2 p = eS[e];
        float4 u = ((const float4*)(h1 + (size_t)p.x * 128))[lane];
        float w = __int_as_float(p.y);
        acc.x += w * u.x; acc.y += w * u.y; acc.z += w * u.z; acc.w += w * u.w;
    }
    float4 b = ((const float4*)b1)[lane];
    acc.x = fmaxf(acc.x + b.x, 0.f);
    acc.y = fmaxf(acc.y + b.y, 0.f);
    acc.z = fmaxf(acc.z + b.z, 0.f);
    acc.w = fmaxf(acc.w + b.w, 0.f);
    ((float4*)(h2 + (size_t)g * 128))[lane] = acc;
}

// ---------------- gather layer 2 (64 f32 cols) + bias ----------------
// 16 lanes per node, 16 nodes per 256-block; 4x unrolled
__global__ __launch_bounds__(256) void gather2_kernel(
        const int2* __restrict__ eS, const int* __restrict__ rowstart,
        const int* __restrict__ deg, const float* __restrict__ dinv,
        const float* __restrict__ h3, const float* __restrict__ b2,
        float* __restrict__ out, int n) {
    int g = blockIdx.x * 16 + (threadIdx.x >> 4);
    int lane = threadIdx.x & 15;
    if (g >= n) return;
    float di = dinv[g];
    float w0 = di * di;
    float4 v = ((const float4*)(h3 + (size_t)g * 64))[lane];
    float4 acc = make_float4(w0 * v.x, w0 * v.y, w0 * v.z, w0 * v.w);
    int beg = rowstart[g], end = beg + deg[g];
    int e = beg;
    for (; e + 4 <= end; e += 4) {
        int2 p0 = eS[e], p1 = eS[e + 1], p2 = eS[e + 2], p3 = eS[e + 3];
        float4 u0 = ((const float4*)(h3 + (size_t)p0.x * 64))[lane];
        float4 u1 = ((const float4*)(h3 + (size_t)p1.x * 64))[lane];
        float4 u2 = ((const float4*)(h3 + (size_t)p2.x * 64))[lane];
        float4 u3 = ((const float4*)(h3 + (size_t)p3.x * 64))[lane];
        float w0f = __int_as_float(p0.y), w1f = __int_as_float(p1.y);
        float w2f = __int_as_float(p2.y), w3f = __int_as_float(p3.y);
        acc.x += w0f * u0.x; acc.y += w0f * u0.y; acc.z += w0f * u0.z; acc.w += w0f * u0.w;
        acc.x += w1f * u1.x; acc.y += w1f * u1.y; acc.z += w1f * u1.z; acc.w += w1f * u1.w;
        acc.x += w2f * u2.x; acc.y += w2f * u2.y; acc.z += w2f * u2.z; acc.w += w2f * u2.w;
        acc.x += w3f * u3.x; acc.y += w3f * u3.y; acc.z += w3f * u3.z; acc.w += w3f * u3.w;
    }
    for (; e < end; e++) {
        int2 p = eS[e];
        float4 u = ((const float4*)(h3 + (size_t)p.x * 64))[lane];
        float w = __int_as_float(p.y);
        acc.x += w * u.x; acc.y += w * u.y; acc.z += w * u.z; acc.w += w * u.w;
    }
    float4 b = ((const float4*)b2)[lane];
    acc.x += b.x; acc.y += b.y; acc.z += b.z; acc.w += b.w;
    ((float4*)(out + (size_t)g * 64))[lane] = acc;
}

extern "C" void kernel_launch(void* const* d_in, const int* in_sizes, int n_in,
                              void* d_out, int out_size, void* d_ws, size_t ws_size,
                              hipStream_t stream) {
    const float* x  = (const float*)d_in[0];
    const int*   ei = (const int*)d_in[1];
    const float* W1 = (const float*)d_in[2];
    const float* b1 = (const float*)d_in[3];
    const float* W2 = (const float*)d_in[4];
    const float* b2 = (const float*)d_in[5];
    float* out = (float*)d_out;

    const int n = in_sizes[0] / 128;   // 100000
    const int E = in_sizes[1] / 2;     // 1600000
    const int* src = ei;
    const int* dst = ei + E;
    const int nb = (n + 255) / 256;

    char* ws = (char*)d_ws;
    size_t off = 0;
    auto carve = [&](size_t bytes) -> char* {
        char* p = ws + off;
        off += (bytes + 255) & ~(size_t)255;
        return p;
    };
    int*   deg        = (int*)carve((size_t)n * 4);
    float* dinv       = (float*)carve((size_t)n * 4);
    int*   rowstart   = (int*)carve((size_t)n * 4);
    int*   cursor     = (int*)carve((size_t)n * 4);
    int*   blockSums  = (int*)carve((size_t)nb * 4);
    int2*  edgeSorted = (int2*)carve((size_t)E * 8);
    float* bufA       = (float*)carve((size_t)n * 128 * 4);  // h1, then h3
    float* bufB       = (float*)carve((size_t)n * 128 * 4);  // h2

    hipMemsetAsync(deg, 0, (size_t)n * 4, stream);

    deg_kernel<<<(E + 255) / 256, 256, 0, stream>>>(dst, deg, E);
    dinv_kernel<<<(n + 255) / 256, 256, 0, stream>>>(deg, dinv, n);
    scan1_kernel<<<nb, 256, 0, stream>>>(deg, rowstart, blockSums, n);
    scan2_kernel<<<1, 512, 0, stream>>>(blockSums, nb);
    scan3_kernel<<<(n + 255) / 256, 256, 0, stream>>>(rowstart, blockSums, cursor, n);
    sort_kernel<<<(E + 255) / 256, 256, 0, stream>>>(src, dst, dinv, cursor, edgeSorted, E);

    // layer 1: h1 = x@W1 ; h2 = relu(agg(h1) + b1)
    gemm_nk128<<<n / 32, 256, 0, stream>>>(x, W1, bufA);
    gather1_kernel<<<(n + 7) / 8, 256, 0, stream>>>(edgeSorted, rowstart, deg, dinv, bufA, b1, bufB, n);

    // layer 2: h3 = h2@W2 (reuse bufA) ; out = agg(h3) + b2
    gemm_nk64<<<n / 32, 256, 0, stream>>>(bufB, W2, bufA);
    gather2_kernel<<<(n + 15) / 16, 256, 0, stream>>>(edgeSorted, rowstart, deg, dinv, bufA, b2, out, n);
}